// Round 7
// baseline (975.157 us; speedup 1.0000x reference)
//
#include <hip/hip_runtime.h>
#include <stdint.h>

// Self-attention, SEQ=8192, D=768, single head.
//   K0a: x fp32->bf16; K0b: Wq/Wk/Wv fp32->bf16 (z-fused)
//   K1a: Q,K projections z-fused (MODE 0); K1b: Vt = Wv x^T (MODE 0)
//   K2 : P' = exp(Q K^T) bf16 + atomic row sums (MODE 1)
//   K3 : out += (P'_chunk V)/rowsum, split-K x4, fp32 atomicAdd (MODE 2)
// R4: XCD swizzle (M on blockIdx.x) -> FETCH at unique-bytes floor.
// R5: BK=64 + XOR swizzle -> conflicts 0. R6: explicit LDS dbuf -> NEUTRAL
//     (= learn_hip m99/m100): compiler's vmcnt(0) before s_barrier drains the
//     prefetch too; ~2 blocks/CU can't hide it. Barrier+LDS K-loop is a
//     structural ~600 TF plateau (m131-m141).
// R7 change: NO LDS, NO BARRIER. Each wave loads its MFMA fragments directly
//     global->VGPR (bf16x8 = global_load_dwordx4; A-layout row=lr,k=quad*8 is
//     16B/lane contiguous). Compiler can now pipeline loads across iters with
//     fine-grained vmcnt(N) (AITER flatmm pattern). Cost: 2x L2 amplification
//     (no intra-block reuse) -- covered by XCD-local L2 at 34.5 TB/s.

#define SEQ    8192
#define DMODEL 768
#define KSPLIT 4

typedef short bf16x8 __attribute__((ext_vector_type(8)));
typedef float f32x4  __attribute__((ext_vector_type(4)));

__device__ __forceinline__ unsigned short f2bf(float f) {
  union { float f; unsigned int u; } v; v.f = f;
  unsigned int u = v.u;
  u += 0x7FFFu + ((u >> 16) & 1u);   // round-to-nearest-even
  return (unsigned short)(u >> 16);
}

__global__ void convert_x(const float* __restrict__ src,
                          unsigned short* __restrict__ dst, int n4) {
  int i = blockIdx.x * blockDim.x + threadIdx.x;
  if (i >= n4) return;
  const float4 f = ((const float4*)src)[i];
  ushort4 o;
  o.x = f2bf(f.x); o.y = f2bf(f.y); o.z = f2bf(f.z); o.w = f2bf(f.w);
  ((ushort4*)dst)[i] = o;
}

__global__ void convert_w(const float* __restrict__ s0, const float* __restrict__ s1,
                          const float* __restrict__ s2,
                          unsigned short* __restrict__ d0, unsigned short* __restrict__ d1,
                          unsigned short* __restrict__ d2, int n4) {
  const float* s = (blockIdx.z == 0) ? s0 : (blockIdx.z == 1) ? s1 : s2;
  unsigned short* d = (blockIdx.z == 0) ? d0 : (blockIdx.z == 1) ? d1 : d2;
  int i = blockIdx.x * blockDim.x + threadIdx.x;
  if (i >= n4) return;
  const float4 f = ((const float4*)s)[i];
  ushort4 o;
  o.x = f2bf(f.x); o.y = f2bf(f.y); o.z = f2bf(f.z); o.w = f2bf(f.w);
  ((ushort4*)d)[i] = o;
}

// C[m,n] = sum_k A[m,k]*B[n,k]  (A:[M,K], B:[N,K] bf16 row-major)
// GRID: blockIdx.x = M-tile, blockIdx.y = N-tile (same-A blocks -> same XCD)
// LDS-FREE: per 32-wide K-step each wave loads 8 fragments (16B/lane,
// global_load_dwordx4) straight into VGPRs and issues 16 MFMA. No barrier
// in the loop => compiler pipelines loads across iterations (vmcnt(N)).
// MODE 0: bf16 C*alpha; z=1 uses B2/Cout2/alpha2 (QK fusion)
// MODE 1: bf16 exp(C) + atomicAdd per-row exp-sums into rowsum
// MODE 2: split-K over z (kChunk each); atomicAdd fp32 C/rowsum[m] into Cout
template <int MODE>
__launch_bounds__(256, 3)
__global__ void gemm_bt(const unsigned short* __restrict__ A,
                        const unsigned short* __restrict__ B,
                        void* __restrict__ Cout,
                        int M, int N, int K, float alpha,
                        float* __restrict__ rowsum, int kChunk,
                        const unsigned short* __restrict__ B2,
                        void* __restrict__ Cout2, float alpha2) {
  if (MODE == 0) {
    if (blockIdx.z == 1) { B = B2; Cout = Cout2; alpha = alpha2; }
  }
  const int kOff = (MODE == 2) ? blockIdx.z * kChunk : 0;

  const int t    = threadIdx.x;
  const int w    = t >> 6;
  const int l    = t & 63;
  const int quad = l >> 4;
  const int lr   = l & 15;
  const int m0   = blockIdx.x * 128;
  const int n0   = blockIdx.y * 128;
  const int wm   = (w & 1) * 64;
  const int wn   = (w >> 1) * 64;

  // Per-lane fragment base pointers (16x16x32 A-operand: row=lr, k=quad*8+j)
  const unsigned short* pA = A + (size_t)(m0 + wm + lr) * K + quad * 8 + kOff;
  const unsigned short* pB = B + (size_t)(n0 + wn + lr) * K + quad * 8 + kOff;
  const size_t rstep = (size_t)16 * K;   // 16 rows

  f32x4 acc[4][4] = {};

  for (int k0 = 0; k0 < kChunk; k0 += 32) {
    bf16x8 af[4], bfr[4];
#pragma unroll
    for (int i = 0; i < 4; ++i) {
      af[i]  = *(const bf16x8*)(pA + i * rstep + k0);
      bfr[i] = *(const bf16x8*)(pB + i * rstep + k0);
    }
#pragma unroll
    for (int mi = 0; mi < 4; ++mi)
#pragma unroll
      for (int ni = 0; ni < 4; ++ni)
        acc[mi][ni] = __builtin_amdgcn_mfma_f32_16x16x32_bf16(af[mi], bfr[ni],
                                                              acc[mi][ni], 0, 0, 0);
  }

  // C/D layout (verified m89): col = lane&15, row = quad*4 + reg
  if (MODE == 0) {
    unsigned short* C = (unsigned short*)Cout;
#pragma unroll
    for (int mi = 0; mi < 4; ++mi)
#pragma unroll
      for (int r = 0; r < 4; ++r) {
        int m = m0 + wm + mi * 16 + quad * 4 + r;
#pragma unroll
        for (int ni = 0; ni < 4; ++ni) {
          int n = n0 + wn + ni * 16 + lr;
          C[(size_t)m * N + n] = f2bf(acc[mi][ni][r] * alpha);
        }
      }
  } else if (MODE == 1) {
    unsigned short* C = (unsigned short*)Cout;
#pragma unroll
    for (int mi = 0; mi < 4; ++mi)
#pragma unroll
      for (int r = 0; r < 4; ++r) {
        int m = m0 + wm + mi * 16 + quad * 4 + r;
        float s = 0.f;
#pragma unroll
        for (int ni = 0; ni < 4; ++ni) {
          int n = n0 + wn + ni * 16 + lr;
          float p = __expf(acc[mi][ni][r]);
          C[(size_t)m * N + n] = f2bf(p);
          s += p;
        }
#pragma unroll
        for (int off = 1; off < 16; off <<= 1) s += __shfl_xor(s, off, 64);
        if (lr == 0) atomicAdd(&rowsum[m], s);
      }
  } else {
    float* C = (float*)Cout;   // d_out fp32, zero-initialized; split-K partials
#pragma unroll
    for (int mi = 0; mi < 4; ++mi)
#pragma unroll
      for (int r = 0; r < 4; ++r) {
        int m = m0 + wm + mi * 16 + quad * 4 + r;
        float inv = 1.0f / rowsum[m];
#pragma unroll
        for (int ni = 0; ni < 4; ++ni) {
          int n = n0 + wn + ni * 16 + lr;
          atomicAdd(&C[(size_t)m * N + n], acc[mi][ni][r] * inv);
        }
      }
  }
}

extern "C" void kernel_launch(void* const* d_in, const int* in_sizes, int n_in,
                              void* d_out, int out_size, void* d_ws, size_t ws_size,
                              hipStream_t stream) {
  const float* x  = (const float*)d_in[0];
  const float* Wq = (const float*)d_in[1];
  const float* Wk = (const float*)d_in[2];
  const float* Wv = (const float*)d_in[3];

  char* ws = (char*)d_ws;
  unsigned short* xb     = (unsigned short*)(ws + 0);
  unsigned short* Qb     = (unsigned short*)(ws + 12582912);
  unsigned short* Kb     = (unsigned short*)(ws + 25165824);
  unsigned short* Vtb    = (unsigned short*)(ws + 37748736);
  unsigned short* wqb    = (unsigned short*)(ws + 50331648);
  unsigned short* wkb    = (unsigned short*)(ws + 51511296);
  unsigned short* wvb    = (unsigned short*)(ws + 52690944);
  float*          rowsum = (float*)(ws + 53870592);
  unsigned short* Pb     = (unsigned short*)(ws + 53903360);
  const size_t need = 53903360u + (size_t)SEQ * SEQ * 2u;
  if (ws_size < need) return;

  hipMemsetAsync(rowsum, 0, SEQ * sizeof(float), stream);
  hipMemsetAsync(d_out, 0, (size_t)out_size * sizeof(float), stream);

  convert_x<<<SEQ * DMODEL / 1024, 256, 0, stream>>>(x, xb, SEQ * DMODEL / 4);
  convert_w<<<dim3(DMODEL * DMODEL / 1024, 1, 3), 256, 0, stream>>>(
      Wq, Wk, Wv, wqb, wkb, wvb, DMODEL * DMODEL / 4);

  const float alpha_q = 0.03608439182435161f;  // 1/sqrt(768)
  dim3 blk(256);
  // grid.x = M-tiles, grid.y = N-tiles (XCD L2 locality)
  gemm_bt<0><<<dim3(SEQ / 128, DMODEL / 128, 2), blk, 0, stream>>>(
      xb, wqb, Qb, SEQ, DMODEL, DMODEL, alpha_q, nullptr, DMODEL,
      wkb, Kb, 1.0f);
  gemm_bt<0><<<dim3(DMODEL / 128, SEQ / 128, 1), blk, 0, stream>>>(
      wvb, xb, Vtb, DMODEL, SEQ, DMODEL, 1.0f, nullptr, DMODEL,
      nullptr, nullptr, 1.0f);
  gemm_bt<1><<<dim3(SEQ / 128, SEQ / 128, 1), blk, 0, stream>>>(
      Qb, Kb, Pb, SEQ, SEQ, DMODEL, 1.0f, rowsum, DMODEL,
      nullptr, nullptr, 1.0f);
  gemm_bt<2><<<dim3(SEQ / 128, DMODEL / 128, KSPLIT), blk, 0, stream>>>(
      Pb, Vtb, d_out, SEQ, DMODEL, SEQ, 1.0f, rowsum, SEQ / KSPLIT,
      nullptr, nullptr, 1.0f);
}

// Round 8
// 420.352 us; speedup vs baseline: 2.3199x; 2.3199x over previous
//
#include <hip/hip_runtime.h>
#include <stdint.h>

// Self-attention, SEQ=8192, D=768, single head.
//   K0a: x fp32->bf16; K0b: Wq/Wk/Wv fp32->bf16 (z-fused)
//   K1a: Q,K projections z-fused (MODE 0); K1b: Vt = Wv x^T (MODE 0)
//   K2 : P' = exp(Q K^T) bf16 + atomic row sums (MODE 1)
//   K3 : out += (P'_chunk V)/rowsum, split-K x4, fp32 atomicAdd (MODE 2)
// R4: XCD swizzle -> FETCH at unique floor. R5: BK=64+XOR swizzle, 0 conflicts,
//     433us. R6: explicit dbuf NEUTRAL (=m99/m100). R7: LDS-free REGRESSED 2.6x
//     (VGPR 56: compiler won't build a vmcnt(N) pipeline; m131-m141 confirmed).
// R8: back to R5 backbone + (a) 32x32x16 MFMA (higher ceiling, half the
//     instructions, 16-reg fragment liveness) + (b) __launch_bounds__(256,4)
//     => 4 blocks/CU (was 3) to cover the vmcnt(0)+s_barrier drain.

#define SEQ    8192
#define DMODEL 768
#define KSPLIT 4

typedef short bf16x8 __attribute__((ext_vector_type(8)));
typedef float f32x4  __attribute__((ext_vector_type(4)));
typedef float f32x16 __attribute__((ext_vector_type(16)));

__device__ __forceinline__ unsigned short f2bf(float f) {
  union { float f; unsigned int u; } v; v.f = f;
  unsigned int u = v.u;
  u += 0x7FFFu + ((u >> 16) & 1u);   // round-to-nearest-even
  return (unsigned short)(u >> 16);
}

__device__ __forceinline__ void async16(void* lds, const void* g) {
  __builtin_amdgcn_global_load_lds((const __attribute__((address_space(1))) void*)g,
                                   (__attribute__((address_space(3))) void*)lds,
                                   16, 0, 0);
}

__global__ void convert_x(const float* __restrict__ src,
                          unsigned short* __restrict__ dst, int n4) {
  int i = blockIdx.x * blockDim.x + threadIdx.x;
  if (i >= n4) return;
  const float4 f = ((const float4*)src)[i];
  ushort4 o;
  o.x = f2bf(f.x); o.y = f2bf(f.y); o.z = f2bf(f.z); o.w = f2bf(f.w);
  ((ushort4*)dst)[i] = o;
}

__global__ void convert_w(const float* __restrict__ s0, const float* __restrict__ s1,
                          const float* __restrict__ s2,
                          unsigned short* __restrict__ d0, unsigned short* __restrict__ d1,
                          unsigned short* __restrict__ d2, int n4) {
  const float* s = (blockIdx.z == 0) ? s0 : (blockIdx.z == 1) ? s1 : s2;
  unsigned short* d = (blockIdx.z == 0) ? d0 : (blockIdx.z == 1) ? d1 : d2;
  int i = blockIdx.x * blockDim.x + threadIdx.x;
  if (i >= n4) return;
  const float4 f = ((const float4*)s)[i];
  ushort4 o;
  o.x = f2bf(f.x); o.y = f2bf(f.y); o.z = f2bf(f.z); o.w = f2bf(f.w);
  ((ushort4*)d)[i] = o;
}

// C[m,n] = sum_k A[m,k]*B[n,k]  (A:[M,K], B:[N,K] bf16 row-major)
// GRID: blockIdx.x = M-tile, blockIdx.y = N-tile (same-A blocks -> same XCD)
// BK=64 single-buffered LDS [128][64] with XOR-chunk swizzle (16B chunks):
//   LDS chunk (row, j) holds global k-chunk j^(row&7); reader wants global
//   chunk g at row r -> LDS chunk g^(r&7). 0 bank conflicts (measured R5).
// MFMA 32x32x16: wave quadrant 64x64 = 2x2 tiles of 32x32 (f32x16 acc).
//   A-op: row=lane&31, k=(lane>>5)*8+j (doubling symmetry of the verified
//   16x16x32 layout). C/D: col=lane&31, row=(reg&3)+8*(reg>>2)+4*(lane>>5)
//   [m74/m101 HW-verified].
// MODE 0: bf16 C*alpha; z=1 uses B2/Cout2/alpha2 (QK fusion)
// MODE 1: bf16 exp(C) + atomicAdd per-row exp-sums into rowsum
// MODE 2: split-K over z (kChunk each); atomicAdd fp32 C/rowsum[m] into Cout
template <int MODE>
__launch_bounds__(256, 4)
__global__ void gemm_bt(const unsigned short* __restrict__ A,
                        const unsigned short* __restrict__ B,
                        void* __restrict__ Cout,
                        int M, int N, int K, float alpha,
                        float* __restrict__ rowsum, int kChunk,
                        const unsigned short* __restrict__ B2,
                        void* __restrict__ Cout2, float alpha2) {
  __shared__ __align__(16) unsigned short lA[128 * 64];
  __shared__ __align__(16) unsigned short lB[128 * 64];

  if (MODE == 0) {
    if (blockIdx.z == 1) { B = B2; Cout = Cout2; alpha = alpha2; }
  }
  const int kOff = (MODE == 2) ? blockIdx.z * kChunk : 0;

  const int t    = threadIdx.x;
  const int w    = t >> 6;
  const int l    = t & 63;
  const int r32  = l & 31;     // row within a 32-tile / output col
  const int kh   = l >> 5;     // k-half selector
  const int m0   = blockIdx.x * 128;
  const int n0   = blockIdx.y * 128;
  const int wm   = (w & 1) * 64;
  const int wn   = (w >> 1) * 64;

  f32x16 acc[2][2] = {};

  const int nk = kChunk >> 6;
  for (int kt = 0; kt < nk; ++kt) {
    const int k0 = kOff + (kt << 6);
    __syncthreads();
    // Stage 128x64 tiles: 1024 x 16B chunks per tensor, 4 per thread.
    // chunk c -> row=c>>3, LDS col-chunk j=c&7 holds global chunk j^(row&7).
#pragma unroll
    for (int h = 0; h < 4; ++h) {
      int c   = t + (h << 8);
      int row = c >> 3;
      int swz = (c & 7) ^ (row & 7);
      async16(&lA[c << 3], A + (size_t)(m0 + row) * K + k0 + (swz << 3));
      async16(&lB[c << 3], B + (size_t)(n0 + row) * K + k0 + (swz << 3));
    }
    __syncthreads();

#pragma unroll
    for (int ks = 0; ks < 4; ++ks) {
      const int g  = (ks << 1) | kh;                 // global 16B k-chunk 0..7
      const int sc = ((g ^ (r32 & 7)) << 3);         // swizzled LDS chunk off
      bf16x8 aT[2], bT[2];
      aT[0] = *(const bf16x8*)&lA[(wm +      r32) * 64 + sc];
      aT[1] = *(const bf16x8*)&lA[(wm + 32 + r32) * 64 + sc];
      bT[0] = *(const bf16x8*)&lB[(wn +      r32) * 64 + sc];
      bT[1] = *(const bf16x8*)&lB[(wn + 32 + r32) * 64 + sc];
      acc[0][0] = __builtin_amdgcn_mfma_f32_32x32x16_bf16(aT[0], bT[0], acc[0][0], 0, 0, 0);
      acc[0][1] = __builtin_amdgcn_mfma_f32_32x32x16_bf16(aT[0], bT[1], acc[0][1], 0, 0, 0);
      acc[1][0] = __builtin_amdgcn_mfma_f32_32x32x16_bf16(aT[1], bT[0], acc[1][0], 0, 0, 0);
      acc[1][1] = __builtin_amdgcn_mfma_f32_32x32x16_bf16(aT[1], bT[1], acc[1][1], 0, 0, 0);
    }
  }

  // C/D 32x32 (m74/m101): col = lane&31, row = (reg&3) + 8*(reg>>2) + 4*kh
  if (MODE == 0) {
    unsigned short* C = (unsigned short*)Cout;
#pragma unroll
    for (int mi = 0; mi < 2; ++mi)
#pragma unroll
      for (int reg = 0; reg < 16; ++reg) {
        int m = m0 + wm + mi * 32 + (reg & 3) + ((reg >> 2) << 3) + (kh << 2);
#pragma unroll
        for (int ni = 0; ni < 2; ++ni) {
          int n = n0 + wn + ni * 32 + r32;
          C[(size_t)m * N + n] = f2bf(acc[mi][ni][reg] * alpha);
        }
      }
  } else if (MODE == 1) {
    unsigned short* C = (unsigned short*)Cout;
#pragma unroll
    for (int mi = 0; mi < 2; ++mi)
#pragma unroll
      for (int reg = 0; reg < 16; ++reg) {
        int m = m0 + wm + mi * 32 + (reg & 3) + ((reg >> 2) << 3) + (kh << 2);
        float s = 0.f;
#pragma unroll
        for (int ni = 0; ni < 2; ++ni) {
          int n = n0 + wn + ni * 32 + r32;
          float p = __expf(acc[mi][ni][reg]);
          C[(size_t)m * N + n] = f2bf(p);
          s += p;
        }
        // reduce over the 32 lanes (r32) sharing this row
#pragma unroll
        for (int off = 1; off < 32; off <<= 1) s += __shfl_xor(s, off, 64);
        if (r32 == 0) atomicAdd(&rowsum[m], s);
      }
  } else {
    float* C = (float*)Cout;   // d_out fp32, zero-initialized; split-K partials
#pragma unroll
    for (int mi = 0; mi < 2; ++mi)
#pragma unroll
      for (int reg = 0; reg < 16; ++reg) {
        int m = m0 + wm + mi * 32 + (reg & 3) + ((reg >> 2) << 3) + (kh << 2);
        float inv = 1.0f / rowsum[m];
#pragma unroll
        for (int ni = 0; ni < 2; ++ni) {
          int n = n0 + wn + ni * 32 + r32;
          atomicAdd(&C[(size_t)m * N + n], acc[mi][ni][reg] * inv);
        }
      }
  }
}

extern "C" void kernel_launch(void* const* d_in, const int* in_sizes, int n_in,
                              void* d_out, int out_size, void* d_ws, size_t ws_size,
                              hipStream_t stream) {
  const float* x  = (const float*)d_in[0];
  const float* Wq = (const float*)d_in[1];
  const float* Wk = (const float*)d_in[2];
  const float* Wv = (const float*)d_in[3];

  char* ws = (char*)d_ws;
  unsigned short* xb     = (unsigned short*)(ws + 0);
  unsigned short* Qb     = (unsigned short*)(ws + 12582912);
  unsigned short* Kb     = (unsigned short*)(ws + 25165824);
  unsigned short* Vtb    = (unsigned short*)(ws + 37748736);
  unsigned short* wqb    = (unsigned short*)(ws + 50331648);
  unsigned short* wkb    = (unsigned short*)(ws + 51511296);
  unsigned short* wvb    = (unsigned short*)(ws + 52690944);
  float*          rowsum = (float*)(ws + 53870592);
  unsigned short* Pb     = (unsigned short*)(ws + 53903360);
  const size_t need = 53903360u + (size_t)SEQ * SEQ * 2u;
  if (ws_size < need) return;

  hipMemsetAsync(rowsum, 0, SEQ * sizeof(float), stream);
  hipMemsetAsync(d_out, 0, (size_t)out_size * sizeof(float), stream);

  convert_x<<<SEQ * DMODEL / 1024, 256, 0, stream>>>(x, xb, SEQ * DMODEL / 4);
  convert_w<<<dim3(DMODEL * DMODEL / 1024, 1, 3), 256, 0, stream>>>(
      Wq, Wk, Wv, wqb, wkb, wvb, DMODEL * DMODEL / 4);

  const float alpha_q = 0.03608439182435161f;  // 1/sqrt(768)
  dim3 blk(256);
  // grid.x = M-tiles, grid.y = N-tiles (XCD L2 locality)
  gemm_bt<0><<<dim3(SEQ / 128, DMODEL / 128, 2), blk, 0, stream>>>(
      xb, wqb, Qb, SEQ, DMODEL, DMODEL, alpha_q, nullptr, DMODEL,
      wkb, Kb, 1.0f);
  gemm_bt<0><<<dim3(DMODEL / 128, SEQ / 128, 1), blk, 0, stream>>>(
      wvb, xb, Vtb, DMODEL, SEQ, DMODEL, 1.0f, nullptr, DMODEL,
      nullptr, nullptr, 1.0f);
  gemm_bt<1><<<dim3(SEQ / 128, SEQ / 128, 1), blk, 0, stream>>>(
      Qb, Kb, Pb, SEQ, SEQ, DMODEL, 1.0f, rowsum, DMODEL,
      nullptr, nullptr, 1.0f);
  gemm_bt<2><<<dim3(SEQ / 128, DMODEL / 128, KSPLIT), blk, 0, stream>>>(
      Pb, Vtb, d_out, SEQ, DMODEL, SEQ, 1.0f, rowsum, SEQ / KSPLIT,
      nullptr, nullptr, 1.0f);
}